// Round 16
// baseline (195.509 us; speedup 1.0000x reference)
//
#include <hip/hip_runtime.h>

#define H 512
#define W 512
#define SLAB 16             // input rows per slab
#define TGR  20             // staged target rows per slab (+-2 halo)
#define NSLAB 4             // slabs per block => 64 rows per block
#define NWAVE 8

// Full-wave (64-lane) sum using DPP only — pure VALU. Result in lane 63.
__device__ __forceinline__ float wave_sum_dpp(float x) {
#define DPP_STEP(ctrl)                                                          \
    x += __int_as_float(__builtin_amdgcn_update_dpp(                            \
        0, __float_as_int(x), (ctrl), 0xF, 0xF, true))
    DPP_STEP(0x111);   // row_shr:1
    DPP_STEP(0x112);   // row_shr:2
    DPP_STEP(0x114);   // row_shr:4
    DPP_STEP(0x118);   // row_shr:8
    DPP_STEP(0x142);   // row_bcast:15
    DPP_STEP(0x143);   // row_bcast:31
#undef DPP_STEP
    return x;
}

__device__ __forceinline__ float4 ld4(const float* p) {
    return *reinterpret_cast<const float4*>(p);
}

// Async global->LDS DMA, 16 B/lane, linear dest (base + lane*16).
__device__ __forceinline__ void gl_lds16(const float* g, float* l) {
    __builtin_amdgcn_global_load_lds(
        (const __attribute__((address_space(1))) void*)g,
        (__attribute__((address_space(3))) void*)l,
        16, 0, 0);
}

// Counted vmcnt wait (never 0 in the loop) + sched fence (rule #18).
#define WAITV(n) do { asm volatile("s_waitcnt vmcnt(" #n ")" ::: "memory");     \
                      __builtin_amdgcn_sched_barrier(0); } while (0)
#define RAWBAR() asm volatile("s_barrier" ::: "memory")

// Kernel 1: counted-vmcnt 2-phase slab pipeline with exact-fit LDS.
// 512 blocks (2/CU) x 512 thr; block owns 64 rows = 4 slabs of 16.
// Per slab: WAITV(4) retires DMA(s) FIFO-exactly (the 4 newest outstanding ops
// are this slab's register input loads); raw s_barrier publishes LDS without
// draining DMA(s+1); STAGE(s+1) rides out during compute(s).
__global__ __launch_bounds__(512, 4)
void dice_partial(const float* __restrict__ in, const float* __restrict__ tg,
                  float* __restrict__ ws, int nblocks) {
    __shared__ __align__(16) float buf[2][TGR * W];   // 81920 B == exactly 2/CU

    const int tid  = threadIdx.x;
    const int wave = tid >> 6, lane = tid & 63;
    const int r    = tid >> 5;            // local input row 0..15 (32 thr/row)
    const int c0   = (tid & 31) * 16;     // my 16 columns

    // Bijective XCD chunking (512 % 8 == 0).
    const int bid = blockIdx.x;
    const int wrk = (bid & 7) * (nblocks >> 3) + (bid >> 3);
    const int b   = wrk >> 3;             // image (8 blocks per image)
    const int r0  = (wrk & 7) * (NSLAB * SLAB);
    const float* __restrict__ inb = in + (size_t)b * (H * W);
    const float* __restrict__ tgb = tg + (size_t)b * (H * W);

    // 40 DMA events per slab (20 rows x 2 halves), 5 per wave.
#define STAGE(s, sb) {                                                          \
        const int y0s = r0 + (s) * SLAB;                                        \
        _Pragma("unroll")                                                       \
        for (int k = 0; k < 5; ++k) {                                           \
            const int c    = wave * 5 + k;                                      \
            const int rr   = c >> 1;                                            \
            const int half = (c & 1) * 256;                                     \
            gl_lds16(tgb + (size_t)((y0s - 2 + rr) & (H - 1)) * W + half        \
                         + lane * 4,                                            \
                     &buf[sb][rr * W + half]);                                  \
        }                                                                       \
    }
// Opaque pointer pin: plain input loads must not hoist above the DMA issues
// (that would corrupt the vmcnt FIFO count). Data-dependence via volatile asm.
#define PIN(p) { uintptr_t u_ = (uintptr_t)(p);                                 \
                 asm volatile("" : "+v"(u_)); (p) = (const float*)u_; }

    float4 cur0, cur1, cur2, cur3, nxt0, nxt1, nxt2, nxt3;

    STAGE(0, 0)
    {
        const float* ip = inb + (size_t)(r0 + r) * W + c0;
        PIN(ip)
        cur0 = ld4(ip); cur1 = ld4(ip + 4); cur2 = ld4(ip + 8); cur3 = ld4(ip + 12);
    }

    float acc[25];
#pragma unroll
    for (int k = 0; k < 25; ++k) acc[k] = 0.f;
    float isum = 0.f, tsum = 0.f;

#pragma unroll 1
    for (int s = 0; s < NSLAB; ++s) {
        WAITV(4);      // own DMA(s) retired; inputs(s) may stay outstanding
        RAWBAR();      // all waves' DMA(s) retired; compute(s-1) done block-wide

        if (s + 1 < NSLAB) {
            STAGE(s + 1, (s + 1) & 1)
            const float* ip = inb + (size_t)(r0 + (s + 1) * SLAB + r) * W + c0;
            PIN(ip)
            nxt0 = ld4(ip); nxt1 = ld4(ip + 4); nxt2 = ld4(ip + 8); nxt3 = ld4(ip + 12);
        }

        // ---- compute slab s ----
        float iv[16];
        iv[0]  = cur0.x; iv[1]  = cur0.y; iv[2]  = cur0.z; iv[3]  = cur0.w;
        iv[4]  = cur1.x; iv[5]  = cur1.y; iv[6]  = cur1.z; iv[7]  = cur1.w;
        iv[8]  = cur2.x; iv[9]  = cur2.y; iv[10] = cur2.z; iv[11] = cur2.w;
        iv[12] = cur3.x; iv[13] = cur3.y; iv[14] = cur3.z; iv[15] = cur3.w;
#pragma unroll
        for (int j = 0; j < 16; ++j) isum += iv[j];

        const float* base = &buf[s & 1][0];
#pragma unroll
        for (int syi = 0; syi < 5; ++syi) {
            const float* rowp = base + (r + syi) * W;
            float tw[24];                  // tw[c] = target col c0 + c - 4
            const float4 m2 = ld4(rowp + ((c0 - 4) & (W - 1)));
            const float4 f0 = ld4(rowp + c0);
            const float4 f1 = ld4(rowp + c0 + 4);
            const float4 f2 = ld4(rowp + c0 + 8);
            const float4 f3 = ld4(rowp + c0 + 12);
            const float4 p2 = ld4(rowp + ((c0 + 16) & (W - 1)));
            tw[0]  = m2.x; tw[1]  = m2.y; tw[2]  = m2.z; tw[3]  = m2.w;
            tw[4]  = f0.x; tw[5]  = f0.y; tw[6]  = f0.z; tw[7]  = f0.w;
            tw[8]  = f1.x; tw[9]  = f1.y; tw[10] = f1.z; tw[11] = f1.w;
            tw[12] = f2.x; tw[13] = f2.y; tw[14] = f2.z; tw[15] = f2.w;
            tw[16] = f3.x; tw[17] = f3.y; tw[18] = f3.z; tw[19] = f3.w;
            tw[20] = p2.x; tw[21] = p2.y; tw[22] = p2.z; tw[23] = p2.w;

            if (syi == 2) {                // own target row: each elem once
#pragma unroll
                for (int j = 0; j < 16; ++j) tsum += tw[4 + j];
            }
#pragma unroll
            for (int sxi = 0; sxi < 5; ++sxi) {
#pragma unroll
                for (int j = 0; j < 16; ++j)
                    acc[syi * 5 + sxi] += iv[j] * tw[j + 2 + sxi];
            }
        }

        if (s + 1 < NSLAB) {               // rotate input registers
            cur0 = nxt0; cur1 = nxt1; cur2 = nxt2; cur3 = nxt3;
        }
    }
#undef STAGE
#undef PIN

    // ---- per-wave DPP reduction; lane 63 stores straight to ws ----
    const int nent = nblocks * NWAVE;
    const int wb   = bid * NWAVE + wave;
#pragma unroll
    for (int k = 0; k < 25; ++k) {
        const float v = wave_sum_dpp(acc[k]);
        if (lane == 63) ws[(size_t)k * nent + wb] = v;
    }
    {
        const float v = wave_sum_dpp(isum);
        if (lane == 63) ws[(size_t)25 * nent + wb] = v;
        const float u = wave_sum_dpp(tsum);
        if (lane == 63) ws[(size_t)26 * nent + wb] = u;
    }
}

// Kernel 2: 27 blocks, block k tree-reduces the per-wave partials for quantity k.
__global__ __launch_bounds__(256)
void dice_reduce(const float* __restrict__ ws, float* __restrict__ tot, int nent) {
    __shared__ float red[4];
    const int k = blockIdx.x;
    const int tid = threadIdx.x;
    const float* p = ws + (size_t)k * nent;

    float s = 0.f;
    for (int i = tid; i < nent; i += 256) s += p[i];
    s = wave_sum_dpp(s);
    if ((tid & 63) == 63) red[tid >> 6] = s;
    __syncthreads();
    if (tid == 0) tot[k] = red[0] + red[1] + red[2] + red[3];
}

// Kernel 3: one wave — 25-way max + final loss scalar.
__global__ void dice_out(const float* __restrict__ tot, float* __restrict__ out) {
    const int tid = threadIdx.x;   // blockDim = 64
    float v = (tid < 25) ? tot[tid] : -1e30f;
#pragma unroll
    for (int off = 32; off; off >>= 1) v = fmaxf(v, __shfl_down(v, off, 64));
    if (tid == 0) {
        const float denom = tot[25] + tot[26] + 1.0f;   // i_sum + t_sum + SMOOTH
        out[0] = 1.0f - (2.0f * v + 1.0f) / denom;      // min loss == max intersection
    }
}

extern "C" void kernel_launch(void* const* d_in, const int* in_sizes, int n_in,
                              void* d_out, int out_size, void* d_ws, size_t ws_size,
                              hipStream_t stream) {
    const float* inputs  = (const float*)d_in[0];
    const float* targets = (const float*)d_in[1];
    float* out = (float*)d_out;
    float* ws  = (float*)d_ws;

    const int B = in_sizes[0] / (H * W);      // 64
    const int nblocks = B * 8;                // 512 blocks (2 per CU), 64 rows each
    const int nent = nblocks * NWAVE;         // 4096 per quantity

    float* tot = ws + (size_t)27 * nent;      // 27 totals after the table

    dice_partial<<<nblocks, 512, 0, stream>>>(inputs, targets, ws, nblocks);
    dice_reduce<<<27, 256, 0, stream>>>(ws, tot, nent);
    dice_out<<<1, 64, 0, stream>>>(tot, out);
}